// Round 11
// baseline (291.354 us; speedup 1.0000x reference)
//
#include <hip/hip_runtime.h>
#include <hip/hip_bf16.h>

// Problem constants
constexpr int kB   = 2;
constexpr int kH   = 8;
constexpr int kG   = 4;
constexpr int kS   = 14;
constexpr int kSS  = 196;   // S*S
constexpr int kKey = 784;   // G*S*S keys per (b,h)
constexpr int kKeyP = 800;  // keys padded to multiple of 32 for MFMA K-loop
constexpr int kMid = 96;
constexpr int kQR  = 28;    // 4 g * 7 j query rows per attention block
constexpr int kCL  = 788;   // contl row stride in u16 = 197*4 ([ij][m] interleaved)
constexpr float kScl = 0.10206207261596577f; // 1/sqrt(96)
constexpr float kK2  = 0.14724663682f;       // kScl / ln(2)  (exp2 domain)
constexpr float kCc  = 11.5415603272f;       // 8 nats / ln(2): constant softmax shift (exact)

typedef __attribute__((ext_vector_type(8))) short bf16x8;
typedef __attribute__((ext_vector_type(4))) float f32x4;

// ---------------- workspace layout (float elements) ----------------
constexpr size_t SZ_QKb = (size_t)kB*kH*kG*kSS*kMid/2; // 602,112 (bf16 in float units)
constexpr size_t OFF_Qb = 0;                            // Qb bf16 [bh][g*196+ij][96]
constexpr size_t OFF_Kb = OFF_Qb + SZ_QKb;              // Kb bf16 [bh][g*196+ij][96]
constexpr size_t OFF_V  = OFF_Kb + SZ_QKb;              // Vb bf16 CHANNEL-MAJOR [bh][c][800]
constexpr size_t SZ_V   = (size_t)kB*kH*kMid*kKeyP/2;   // 614,400
constexpr size_t OFF_FR = OFF_V + SZ_V;                 // 27*32 row table fp32
constexpr size_t OFF_FC = OFF_FR + 27*32;               // 27*32 col table fp32
constexpr size_t OFF_PS = OFF_FC + 27*32;               // Psum bf16 [bh][v*196+ij][800]
constexpr size_t SZ_PS  = (size_t)kB*kH*kG*kSS*kKeyP/2; // 5,017,600
constexpr size_t OFF_WOH = OFF_PS + SZ_PS;              // Woh bf16 [h][d][c] (73,728)

// ============================================================
// Kernel 1: QKV projection + fused setup (R10-proven, unchanged).
// ============================================================
__global__ __launch_bounds__(256)
void k_qkv(const float* __restrict__ x,
           const float* __restrict__ Wq, const float* __restrict__ bq,
           const float* __restrict__ Wk, const float* __restrict__ bk,
           const float* __restrict__ Wv, const float* __restrict__ bv,
           __hip_bfloat16* __restrict__ Qb, __hip_bfloat16* __restrict__ Kb,
           __hip_bfloat16* __restrict__ Vb,
           const float* __restrict__ rw1, const float* __restrict__ rb1,
           const float* __restrict__ rgam, const float* __restrict__ rbet,
           const float* __restrict__ rw2, const float* __restrict__ rb2,
           const float* __restrict__ cw1, const float* __restrict__ cb1,
           const float* __restrict__ cgam, const float* __restrict__ cbet,
           const float* __restrict__ cw2, const float* __restrict__ cb2,
           float* __restrict__ frow, float* __restrict__ fcol,
           const float* __restrict__ Wo, __hip_bfloat16* __restrict__ Woh,
           float* __restrict__ out0) {
  const int bid = blockIdx.x;
  const int ten = blockIdx.y;
  const int i = bid % 14;
  const int g = (bid / 14) % 4;
  const int b = bid / 56;
  const float* W    = (ten == 0) ? Wq : (ten == 1) ? Wk : Wv;
  const float* bias = (ten == 0) ? bq : (ten == 1) ? bk : bv;

  // ---- zero d_out (atomically accumulated by k_pv; harness poisons it)
  {
    int zidx = (ten*112 + bid)*256 + threadIdx.x;   // 0 .. 86015
    if (zidx < 37632) ((float4*)out0)[zidx] = make_float4(0.f, 0.f, 0.f, 0.f);
  }

  __shared__ alignas(16) float xs[14][100];   // transposed, padded
  for (int idx = threadIdx.x; idx < 96*14; idx += 256) {
    int cin = idx / 14, j = idx % 14;
    xs[j][cin] = x[((size_t)(b*96 + cin)*4 + g)*196 + i*14 + j];
  }
  __syncthreads();

  for (int d = threadIdx.x; d < 768; d += 256) {
    int c = d >> 3, h = d & 7;
    float bvv = bias[d];
    float acc[14];
#pragma unroll
    for (int j = 0; j < 14; ++j) acc[j] = bvv;
    const float* wrow = W + (size_t)d * 96;
    for (int cc = 0; cc < 96; cc += 4) {
      float4 w = *(const float4*)(wrow + cc);
#pragma unroll
      for (int j = 0; j < 14; ++j) {
        float4 xv = *(const float4*)(&xs[j][cc]);
        acc[j] += w.x*xv.x + w.y*xv.y + w.z*xv.z + w.w*xv.w;
      }
    }
    if (ten == 2) {
      __hip_bfloat16* op = Vb + ((size_t)((b*8 + h)*96 + c))*kKeyP + g*196 + i*14;
#pragma unroll
      for (int j = 0; j < 14; ++j) op[j] = __float2bfloat16(acc[j]);
    } else {
      __hip_bfloat16* dst = (ten == 0) ? Qb : Kb;
      __hip_bfloat16* op = dst + ((size_t)((b*8 + h)*4 + g)*196 + i*14)*96 + c;
#pragma unroll
      for (int j = 0; j < 14; ++j) op[(size_t)j*96] = __float2bfloat16(acc[j]);
    }
  }

  // ---- fused setup tails ----
  if (ten == 1) {
    // Woh[h][d][c] = bf16(Wo[d][c*8+h]) -- per-head B-operand for k_pv phase B
    for (int idx = bid*256 + threadIdx.x; idx < 73728; idx += 112*256) {
      int h = idx / 9216, rem = idx - h*9216;
      int d = rem / 96, c = rem - d*96;
      Woh[idx] = __float2bfloat16(Wo[(size_t)d*768 + c*8 + h]);
    }
  }
  if (ten == 2 && bid < 16) {
    // zero V key-pad for bh = bid
    for (int idx = threadIdx.x; idx < 96*16; idx += 256) {
      int c = idx >> 4, kp = idx & 15;
      Vb[((size_t)(bid*96 + c))*kKeyP + kKey + kp] = __float2bfloat16(0.f);
    }
  }
  if (ten == 0 && bid == 0 && threadIdx.x < 54) {
    int t = threadIdx.x;
    int which = t / 27;
    int n = t % 27;
    float tv = (float)(n - 13) / 13.0f;
    const float* w1  = which ? cw1  : rw1;
    const float* b1  = which ? cb1  : rb1;
    const float* gam = which ? cgam : rgam;
    const float* bet = which ? cbet : rbet;
    const float* w2  = which ? cw2  : rw2;
    const float* b2  = which ? cb2  : rb2;
    float h[16];
    float mu = 0.f;
#pragma unroll
    for (int d = 0; d < 16; ++d) { h[d] = tv * w1[d] + b1[d]; mu += h[d]; }
    mu *= (1.0f/16.0f);
    float var = 0.f;
#pragma unroll
    for (int d = 0; d < 16; ++d) { float z = h[d] - mu; var += z*z; }
    var *= (1.0f/16.0f);
    float rstd = rsqrtf(var + 1e-5f);
#pragma unroll
    for (int d = 0; d < 16; ++d) {
      float z = (h[d] - mu) * rstd * gam[d] + bet[d];
      h[d] = z / (1.0f + expf(-z));   // silu
    }
    float* outp = (which ? fcol : frow) + n*32;
    for (int c = 0; c < 32; ++c) {
      float o = b2[c];
#pragma unroll
      for (int d = 0; d < 16; ++d) o += h[d] * w2[d*32 + c];
      outp[c] = o;
    }
  }
}

// ============================================================
// Kernel 2: fused content + bias + softmax -- DE-BARRIERED (13 -> 3).
// - No LDS staging: bias dots read Qb/frow/fcol/gemb from global (L2-hot);
//   kK2 scale applied after the dot (fp32-equivalent).
// - MFMA QK^T -> contl (R10-proven), then E loaded ONCE into packed regs.
// - Pass B for all 4 v back-to-back (no barriers) -> redwAll; one barrier;
//   DinvAll; one barrier; pass C all 4 v barrier-free.
// - AgE rotation folded into compile-time indices (v-loops fully unrolled).
// Block = (b,h,i,jhalf): 28 query rows (4 g x 7 j) vs 784 keys.
// ============================================================
__global__ __launch_bounds__(256, 2)
void k_attn(const __hip_bfloat16* __restrict__ Qb, const __hip_bfloat16* __restrict__ Kb,
            const float* __restrict__ frow_g, const float* __restrict__ fcol_g,
            const float* __restrict__ gemb_g, __hip_bfloat16* __restrict__ Pb) {
  const int tid = threadIdx.x;
  const int bid = blockIdx.x;
  const int jhalf = bid & 1;
  const int t2 = bid >> 1;
  const int qi = t2 % 14;
  const int hh = (t2 / 14) % 8;
  const int bb = t2 / 112;
  const int bh = bb*8 + hh;

  __shared__ alignas(16) __hip_bfloat16 contl[kQR][kCL];  // E: [q][ij*4 + m]
  __shared__ float Arr2[kQR][27];             // row bias dot * kK2
  __shared__ float Acl2[kQR][27];             // col bias dot * kK2
  __shared__ float AgE[kQR][4];               // exp2(group bias * kK2)
  __shared__ float redwAll[4][kQR][4];        // per-v per-wave partials
  __shared__ float DinvAll[4][kQR];

  const short* Qs = (const short*)Qb;
  const short* Ks = (const short*)Kb;

  // ---- MFMA content GEMM -> contl (E = exp2(content*kK2 - Cc), bf16)
  {
    const int lane = tid & 63;
    const int wave = tid >> 6;
    const int col  = lane & 15;
    const int quad = lane >> 4;

    bf16x8 afrag[2][3];
#pragma unroll
    for (int mt = 0; mt < 2; ++mt) {
      int m = mt*16 + col;
      int q = (m < kQR) ? m : 0;                 // pad rows: duplicate q0 (discarded)
      const short* qrow = Qs +
          ((size_t)((bh*4 + q/7)*kSS + qi*14 + jhalf*7 + q%7))*96;
#pragma unroll
      for (int ks = 0; ks < 3; ++ks)
        afrag[mt][ks] = *(const bf16x8*)(qrow + ks*32 + quad*8);
    }

    for (int nt = wave; nt < 49; nt += 4) {
      int kl = nt*16 + col;                      // key index g_key*196 + ij
      const short* krow = Ks + ((size_t)(bh*kKey + kl))*96;
      bf16x8 b0 = *(const bf16x8*)(krow + 0*32 + quad*8);
      bf16x8 b1 = *(const bf16x8*)(krow + 1*32 + quad*8);
      bf16x8 b2 = *(const bf16x8*)(krow + 2*32 + quad*8);
      f32x4 c0 = {0.f,0.f,0.f,0.f};
      f32x4 c1 = {0.f,0.f,0.f,0.f};
      c0 = __builtin_amdgcn_mfma_f32_16x16x32_bf16(afrag[0][0], b0, c0, 0, 0, 0);
      c0 = __builtin_amdgcn_mfma_f32_16x16x32_bf16(afrag[0][1], b1, c0, 0, 0, 0);
      c0 = __builtin_amdgcn_mfma_f32_16x16x32_bf16(afrag[0][2], b2, c0, 0, 0, 0);
      c1 = __builtin_amdgcn_mfma_f32_16x16x32_bf16(afrag[1][0], b0, c1, 0, 0, 0);
      c1 = __builtin_amdgcn_mfma_f32_16x16x32_bf16(afrag[1][1], b1, c1, 0, 0, 0);
      c1 = __builtin_amdgcn_mfma_f32_16x16x32_bf16(afrag[1][2], b2, c1, 0, 0, 0);
      int ijn = kl % 196, mk = kl / 196;         // interleaved store position
      // C/D layout: col = lane&15 (=kl), row = quad*4 + r (=q)  [m89]
#pragma unroll
      for (int r = 0; r < 4; ++r) {
        int q0 = quad*4 + r;                     // 0..15, all valid
        contl[q0][ijn*4 + mk] = __float2bfloat16(exp2f(c0[r]*kK2 - kCc));
        int q1 = 16 + quad*4 + r;                // 16..31, valid < 28
        if (q1 < kQR)
          contl[q1][ijn*4 + mk] = __float2bfloat16(exp2f(c1[r]*kK2 - kCc));
      }
    }
  }

  // ---- per-query bias tables, read straight from global (L2-hot)
  for (int t = tid; t < kQR*58; t += 256) {
    int q = t / 58, s = t - q*58;
    int gq = q / 7, jq = q - gq*7;
    const __hip_bfloat16* qrow =
        Qb + ((size_t)((bh*4 + gq)*kSS + qi*14 + jhalf*7 + jq))*96;
    float acc = 0.f;
    if (s < 27) {
#pragma unroll
      for (int c = 0; c < 32; ++c)
        acc += __bfloat162float(qrow[c]) * frow_g[s*32 + c];
      Arr2[q][s] = acc * kK2;
    } else if (s < 54) {
      int n = s - 27;
#pragma unroll
      for (int c = 0; c < 32; ++c)
        acc += __bfloat162float(qrow[32 + c]) * fcol_g[n*32 + c];
      Acl2[q][n] = acc * kK2;
    } else {
      int p = s - 54;
#pragma unroll
      for (int c = 0; c < 32; ++c)
        acc += __bfloat162float(qrow[64 + c]) * gemb_g[p*32 + c];
      AgE[q][p] = exp2f(acc * kK2);
    }
  }
  __syncthreads();   // ---- barrier 1: contl + tables ready ----

  const int kk = (tid < 196) ? (tid / 14) : 0;
  const int ll = (tid < 196) ? (tid % 14) : 0;
  const int da = kk - qi;

  // ---- E loaded once into packed registers (v-independent)
  uint2 Ep[kQR];
  if (tid < 196) {
#pragma unroll
    for (int q = 0; q < kQR; ++q)
      Ep[q] = *(const uint2*)(&contl[q][tid*4]);
  } else {
#pragma unroll
    for (int q = 0; q < kQR; ++q) { Ep[q].x = 0u; Ep[q].y = 0u; }
  }

  // ---- pass B: denominators for ALL 4 v, no intervening barriers
#pragma unroll
  for (int v = 0; v < 4; ++v) {
    const int s1a = (v == 0) ? 1 : (v == 2) ? -1 : 0;
    const int s1b = (v == 1) ? -1 : (v == 3) ? 1 : 0;
    const int s2a = (v == 1) ? 1 : (v == 3) ? -1 : 0;
    const int s2b = (v == 0) ? 1 : (v == 2) ? -1 : 0;
    float prt[kQR];
    if (tid < 196) {
#pragma unroll
      for (int gq = 0; gq < 4; ++gq) {
#pragma unroll
        for (int jq = 0; jq < 7; ++jq) {
          const int q = gq*7 + jq;
          const int db = ll - (jhalf*7 + jq);
          const int ai = s1a*da + s1b*db, ci = s2a*da + s2b*db;
          float arvE = exp2f(Arr2[q][13 + ai] + Acl2[q][13 + ci]);
          float e0 = __uint_as_float(Ep[q].x << 16);
          float e1 = __uint_as_float(Ep[q].x & 0xffff0000u);
          float e2 = __uint_as_float(Ep[q].y << 16);
          float e3 = __uint_as_float(Ep[q].y & 0xffff0000u);
          prt[q] = (e0*AgE[q][(0 - gq + v + 8) & 3] +
                    e1*AgE[q][(1 - gq + v + 8) & 3] +
                    e2*AgE[q][(2 - gq + v + 8) & 3] +
                    e3*AgE[q][(3 - gq + v + 8) & 3]) * arvE;
        }
      }
    } else {
#pragma unroll
      for (int q = 0; q < kQR; ++q) prt[q] = 0.f;
    }
    // level-outer butterfly: 28 independent shuffles per level (ILP)
#pragma unroll
    for (int off = 1; off < 64; off <<= 1) {
#pragma unroll
      for (int q = 0; q < kQR; ++q)
        prt[q] += __shfl_xor(prt[q], off, 64);
    }
    if ((tid & 63) == 0) {
#pragma unroll
      for (int q = 0; q < kQR; ++q) redwAll[v][q][tid >> 6] = prt[q];
    }
  }
  __syncthreads();   // ---- barrier 2 ----
  if (tid < 112) {
    int v = tid / 28, q = tid - v*28;
    DinvAll[v][q] = 1.0f / (redwAll[v][q][0] + redwAll[v][q][1] +
                            redwAll[v][q][2] + redwAll[v][q][3]);
  }
  __syncthreads();   // ---- barrier 3 ----

  // ---- pass C: normalized probs for all 4 v, barrier-free
  if (tid < 196) {
#pragma unroll
    for (int v = 0; v < 4; ++v) {
      const int s1a = (v == 0) ? 1 : (v == 2) ? -1 : 0;
      const int s1b = (v == 1) ? -1 : (v == 3) ? 1 : 0;
      const int s2a = (v == 1) ? 1 : (v == 3) ? -1 : 0;
      const int s2b = (v == 0) ? 1 : (v == 2) ? -1 : 0;
      __hip_bfloat16* pbase =
          Pb + ((size_t)((bh*4 + v)*kSS + qi*14 + jhalf*7))*kKeyP + tid;
#pragma unroll
      for (int jq = 0; jq < 7; ++jq) {
        const int db = ll - (jhalf*7 + jq);
        const int ai = s1a*da + s1b*db, ci = s2a*da + s2b*db;
        float am[4] = {0.f, 0.f, 0.f, 0.f};
#pragma unroll
        for (int gq = 0; gq < 4; ++gq) {
          const int q = gq*7 + jq;
          float arvE = exp2f(Arr2[q][13 + ai] + Acl2[q][13 + ci]);
          const float fq = arvE * DinvAll[v][q];
          float e0 = __uint_as_float(Ep[q].x << 16);
          float e1 = __uint_as_float(Ep[q].x & 0xffff0000u);
          float e2 = __uint_as_float(Ep[q].y << 16);
          float e3 = __uint_as_float(Ep[q].y & 0xffff0000u);
          am[0] += e0 * (AgE[q][(0 - gq + v + 8) & 3] * fq);
          am[1] += e1 * (AgE[q][(1 - gq + v + 8) & 3] * fq);
          am[2] += e2 * (AgE[q][(2 - gq + v + 8) & 3] * fq);
          am[3] += e3 * (AgE[q][(3 - gq + v + 8) & 3] * fq);
        }
        __hip_bfloat16* pp = pbase + (size_t)jq*kKeyP;
#pragma unroll
        for (int m = 0; m < 4; ++m) pp[m*196] = __float2bfloat16(am[m]);
      }
    }
  }
  // zero the key-pad [784,800) of this block's 7 rows, all v
  if (tid < 112) {
    int jq = tid >> 4, kp = tid & 15;
#pragma unroll
    for (int v = 0; v < 4; ++v)
      Pb[((size_t)((bh*4 + v)*kSS + qi*14 + jhalf*7 + jq))*kKeyP + kKey + kp] =
          __float2bfloat16(0.f);
  }
}

// ============================================================
// Kernel 3: PV + per-head partial output projection (R10-proven, unchanged).
// ============================================================
__global__ __launch_bounds__(128)
void k_pv(const __hip_bfloat16* __restrict__ Pb,
          const __hip_bfloat16* __restrict__ Vb,
          const __hip_bfloat16* __restrict__ Woh,
          const float* __restrict__ bo, float* __restrict__ out) {
  const int tid  = threadIdx.x;
  const int lane = tid & 63;
  const int wave = tid >> 6;
  const int bh = blockIdx.x / 49;
  const int mt = blockIdx.x % 49;
  const int mrow = lane & 15;
  const int quad = lane >> 4;
  const int b_ = bh >> 3, h_ = bh & 7;

  __shared__ alignas(16) __hip_bfloat16 vos[16][104];  // [m-row][c], pad 96->104

  // ---- phase A: PV (this head), 6 N-tiles split 3 per wave
  {
    const short* Ap = (const short*)Pb +
        ((size_t)(bh*kKey + mt*16 + mrow))*kKeyP + quad*8;
    const short* Bp = (const short*)Vb + ((size_t)bh*96)*kKeyP + quad*8;

    f32x4 acc0 = {0.f,0.f,0.f,0.f};
    f32x4 acc1 = {0.f,0.f,0.f,0.f};
    f32x4 acc2 = {0.f,0.f,0.f,0.f};
    const int n0 = (wave*3 + 0)*16 + mrow;
    const int n1 = (wave*3 + 1)*16 + mrow;
    const int n2 = (wave*3 + 2)*16 + mrow;

    for (int ks = 0; ks < kKeyP/32; ++ks) {
      bf16x8 a  = *(const bf16x8*)(Ap + ks*32);
      bf16x8 b0 = *(const bf16x8*)(Bp + (size_t)n0*kKeyP + ks*32);
      bf16x8 b1 = *(const bf16x8*)(Bp + (size_t)n1*kKeyP + ks*32);
      bf16x8 b2 = *(const bf16x8*)(Bp + (size_t)n2*kKeyP + ks*32);
      acc0 = __builtin_amdgcn_mfma_f32_16x16x32_bf16(a, b0, acc0, 0, 0, 0);
      acc1 = __builtin_amdgcn_mfma_f32_16x16x32_bf16(a, b1, acc1, 0, 0, 0);
      acc2 = __builtin_amdgcn_mfma_f32_16x16x32_bf16(a, b2, acc2, 0, 0, 0);
    }
    // C/D: col = lane&15 (= c within n-tile), row = quad*4 + r (= m-row)
#pragma unroll
    for (int r = 0; r < 4; ++r) {
      vos[quad*4 + r][n0] = __float2bfloat16(acc0[r]);
      vos[quad*4 + r][n1] = __float2bfloat16(acc1[r]);
      vos[quad*4 + r][n2] = __float2bfloat16(acc2[r]);
    }
  }
  __syncthreads();

  // ---- phase B: partial outproj for this head, 6 d-tiles split 3 per wave
  const short* wb = (const short*)Woh + (size_t)h_*9216;
#pragma unroll
  for (int w = 0; w < 3; ++w) {
    const int dt = wave*3 + w;
    f32x4 acc = {0.f,0.f,0.f,0.f};
#pragma unroll
    for (int ks = 0; ks < 3; ++ks) {
      bf16x8 a  = *(const bf16x8*)(&vos[mrow][ks*32 + quad*8]);
      bf16x8 bf = *(const bf16x8*)(wb + (size_t)(dt*16 + mrow)*96 + ks*32 + quad*8);
      acc = __builtin_amdgcn_mfma_f32_16x16x32_bf16(a, bf, acc, 0, 0, 0);
    }
    const int d = dt*16 + mrow;                 // D col = lane&15 = d-in-tile
    const float bias = (h_ == 0) ? bo[d] : 0.f;
#pragma unroll
    for (int r = 0; r < 4; ++r) {
      int m = mt*16 + quad*4 + r;
      int v = m / kSS, ij = m - v*kSS;
      atomicAdd(&out[((size_t)(b_*96 + d)*4 + v)*kSS + ij], acc[r] + bias);
    }
  }
}

// ============================================================
extern "C" void kernel_launch(void* const* d_in, const int* in_sizes, int n_in,
                              void* d_out, int out_size, void* d_ws, size_t ws_size,
                              hipStream_t stream) {
  const float* x    = (const float*)d_in[0];
  const float* Wq   = (const float*)d_in[1];
  const float* bq   = (const float*)d_in[2];
  const float* Wk   = (const float*)d_in[3];
  const float* bk   = (const float*)d_in[4];
  const float* Wv   = (const float*)d_in[5];
  const float* bv   = (const float*)d_in[6];
  const float* Wo   = (const float*)d_in[7];
  const float* bo   = (const float*)d_in[8];
  const float* rw1  = (const float*)d_in[9];
  const float* rb1  = (const float*)d_in[10];
  const float* rgam = (const float*)d_in[11];
  const float* rbet = (const float*)d_in[12];
  const float* rw2  = (const float*)d_in[13];
  const float* rb2  = (const float*)d_in[14];
  const float* cw1  = (const float*)d_in[15];
  const float* cb1  = (const float*)d_in[16];
  const float* cgam = (const float*)d_in[17];
  const float* cbet = (const float*)d_in[18];
  const float* cw2  = (const float*)d_in[19];
  const float* cb2  = (const float*)d_in[20];
  const float* gemb = (const float*)d_in[21];
  // d_in[22..24] = row_rel, col_rel, g_idx: reconstructed analytically.

  float* ws = (float*)d_ws;
  __hip_bfloat16* Qb = (__hip_bfloat16*)(ws + OFF_Qb);
  __hip_bfloat16* Kb = (__hip_bfloat16*)(ws + OFF_Kb);
  __hip_bfloat16* Vb = (__hip_bfloat16*)(ws + OFF_V);
  float* Frow = ws + OFF_FR;
  float* Fcol = ws + OFF_FC;
  __hip_bfloat16* Pb = (__hip_bfloat16*)(ws + OFF_PS);
  __hip_bfloat16* Woh = (__hip_bfloat16*)(ws + OFF_WOH);
  float* out  = (float*)d_out;

  k_qkv<<<dim3(112, 3), 256, 0, stream>>>(x, Wq, bq, Wk, bk, Wv, bv, Qb, Kb, Vb,
                                          rw1, rb1, rgam, rbet, rw2, rb2,
                                          cw1, cb1, cgam, cbet, cw2, cb2,
                                          Frow, Fcol, Wo, Woh, out);
  k_attn<<<448, 256, 0, stream>>>(Qb, Kb, Frow, Fcol, gemb, Pb);
  k_pv<<<784, 128, 0, stream>>>(Pb, Vb, Woh, bo, out);
}

// Round 12
// 230.547 us; speedup vs baseline: 1.2638x; 1.2638x over previous
//
#include <hip/hip_runtime.h>
#include <hip/hip_bf16.h>

// Problem constants
constexpr int kB   = 2;
constexpr int kH   = 8;
constexpr int kG   = 4;
constexpr int kS   = 14;
constexpr int kSS  = 196;   // S*S
constexpr int kKey = 784;   // G*S*S keys per (b,h)
constexpr int kKeyP = 800;  // keys padded to multiple of 32 for MFMA K-loop
constexpr int kMid = 96;
constexpr int kQR  = 28;    // 4 g * 7 j query rows per attention block
constexpr int kCL  = 788;   // contl row stride in u16 = 197*4 ([ij][m] interleaved)
constexpr float kScl = 0.10206207261596577f; // 1/sqrt(96)
constexpr float kK2  = 0.14724663682f;       // kScl / ln(2)  (exp2 domain)
constexpr float kCc  = 11.5415603272f;       // 8 nats / ln(2): constant softmax shift (exact)

typedef __attribute__((ext_vector_type(8))) short bf16x8;
typedef __attribute__((ext_vector_type(4))) float f32x4;

// ---------------- workspace layout (float elements) ----------------
constexpr size_t SZ_QKb = (size_t)kB*kH*kG*kSS*kMid/2; // 602,112 (bf16 in float units)
constexpr size_t OFF_Qb = 0;                            // Qb bf16 [bh][g*196+ij][96]
constexpr size_t OFF_Kb = OFF_Qb + SZ_QKb;              // Kb bf16 [bh][g*196+ij][96]
constexpr size_t OFF_V  = OFF_Kb + SZ_QKb;              // Vb bf16 CHANNEL-MAJOR [bh][c][800]
constexpr size_t SZ_V   = (size_t)kB*kH*kMid*kKeyP/2;   // 614,400
constexpr size_t OFF_FR = OFF_V + SZ_V;                 // 27*32 row table fp32
constexpr size_t OFF_FC = OFF_FR + 27*32;               // 27*32 col table fp32
constexpr size_t OFF_PS = OFF_FC + 27*32;               // Psum bf16 [bh][v*196+ij][800]
constexpr size_t SZ_PS  = (size_t)kB*kH*kG*kSS*kKeyP/2; // 5,017,600
constexpr size_t OFF_WOH = OFF_PS + SZ_PS;              // Woh bf16 [h][d][c] (73,728)

// ============================================================
// Kernel 1: QKV projection + fused setup (R10-proven, unchanged).
// ============================================================
__global__ __launch_bounds__(256)
void k_qkv(const float* __restrict__ x,
           const float* __restrict__ Wq, const float* __restrict__ bq,
           const float* __restrict__ Wk, const float* __restrict__ bk,
           const float* __restrict__ Wv, const float* __restrict__ bv,
           __hip_bfloat16* __restrict__ Qb, __hip_bfloat16* __restrict__ Kb,
           __hip_bfloat16* __restrict__ Vb,
           const float* __restrict__ rw1, const float* __restrict__ rb1,
           const float* __restrict__ rgam, const float* __restrict__ rbet,
           const float* __restrict__ rw2, const float* __restrict__ rb2,
           const float* __restrict__ cw1, const float* __restrict__ cb1,
           const float* __restrict__ cgam, const float* __restrict__ cbet,
           const float* __restrict__ cw2, const float* __restrict__ cb2,
           float* __restrict__ frow, float* __restrict__ fcol,
           const float* __restrict__ Wo, __hip_bfloat16* __restrict__ Woh,
           float* __restrict__ out0) {
  const int bid = blockIdx.x;
  const int ten = blockIdx.y;
  const int i = bid % 14;
  const int g = (bid / 14) % 4;
  const int b = bid / 56;
  const float* W    = (ten == 0) ? Wq : (ten == 1) ? Wk : Wv;
  const float* bias = (ten == 0) ? bq : (ten == 1) ? bk : bv;

  // ---- zero d_out (atomically accumulated by k_pv; harness poisons it)
  {
    int zidx = (ten*112 + bid)*256 + threadIdx.x;   // 0 .. 86015
    if (zidx < 37632) ((float4*)out0)[zidx] = make_float4(0.f, 0.f, 0.f, 0.f);
  }

  __shared__ alignas(16) float xs[14][100];   // transposed, padded
  for (int idx = threadIdx.x; idx < 96*14; idx += 256) {
    int cin = idx / 14, j = idx % 14;
    xs[j][cin] = x[((size_t)(b*96 + cin)*4 + g)*196 + i*14 + j];
  }
  __syncthreads();

  for (int d = threadIdx.x; d < 768; d += 256) {
    int c = d >> 3, h = d & 7;
    float bvv = bias[d];
    float acc[14];
#pragma unroll
    for (int j = 0; j < 14; ++j) acc[j] = bvv;
    const float* wrow = W + (size_t)d * 96;
    for (int cc = 0; cc < 96; cc += 4) {
      float4 w = *(const float4*)(wrow + cc);
#pragma unroll
      for (int j = 0; j < 14; ++j) {
        float4 xv = *(const float4*)(&xs[j][cc]);
        acc[j] += w.x*xv.x + w.y*xv.y + w.z*xv.z + w.w*xv.w;
      }
    }
    if (ten == 2) {
      __hip_bfloat16* op = Vb + ((size_t)((b*8 + h)*96 + c))*kKeyP + g*196 + i*14;
#pragma unroll
      for (int j = 0; j < 14; ++j) op[j] = __float2bfloat16(acc[j]);
    } else {
      __hip_bfloat16* dst = (ten == 0) ? Qb : Kb;
      __hip_bfloat16* op = dst + ((size_t)((b*8 + h)*4 + g)*196 + i*14)*96 + c;
#pragma unroll
      for (int j = 0; j < 14; ++j) op[(size_t)j*96] = __float2bfloat16(acc[j]);
    }
  }

  // ---- fused setup tails ----
  if (ten == 1) {
    // Woh[h][d][c] = bf16(Wo[d][c*8+h]) -- per-head B-operand for k_pv phase B
    for (int idx = bid*256 + threadIdx.x; idx < 73728; idx += 112*256) {
      int h = idx / 9216, rem = idx - h*9216;
      int d = rem / 96, c = rem - d*96;
      Woh[idx] = __float2bfloat16(Wo[(size_t)d*768 + c*8 + h]);
    }
  }
  if (ten == 2 && bid < 16) {
    // zero V key-pad for bh = bid
    for (int idx = threadIdx.x; idx < 96*16; idx += 256) {
      int c = idx >> 4, kp = idx & 15;
      Vb[((size_t)(bid*96 + c))*kKeyP + kKey + kp] = __float2bfloat16(0.f);
    }
  }
  if (ten == 0 && bid == 0 && threadIdx.x < 54) {
    int t = threadIdx.x;
    int which = t / 27;
    int n = t % 27;
    float tv = (float)(n - 13) / 13.0f;
    const float* w1  = which ? cw1  : rw1;
    const float* b1  = which ? cb1  : rb1;
    const float* gam = which ? cgam : rgam;
    const float* bet = which ? cbet : rbet;
    const float* w2  = which ? cw2  : rw2;
    const float* b2  = which ? cb2  : rb2;
    float h[16];
    float mu = 0.f;
#pragma unroll
    for (int d = 0; d < 16; ++d) { h[d] = tv * w1[d] + b1[d]; mu += h[d]; }
    mu *= (1.0f/16.0f);
    float var = 0.f;
#pragma unroll
    for (int d = 0; d < 16; ++d) { float z = h[d] - mu; var += z*z; }
    var *= (1.0f/16.0f);
    float rstd = rsqrtf(var + 1e-5f);
#pragma unroll
    for (int d = 0; d < 16; ++d) {
      float z = (h[d] - mu) * rstd * gam[d] + bet[d];
      h[d] = z / (1.0f + expf(-z));   // silu
    }
    float* outp = (which ? fcol : frow) + n*32;
    for (int c = 0; c < 32; ++c) {
      float o = b2[c];
#pragma unroll
      for (int d = 0; d < 16; ++d) o += h[d] * w2[d*32 + c];
      outp[c] = o;
    }
  }
}

// ============================================================
// Kernel 2: fused content + bias + softmax. R10-proven structure (per-v
// loop, arvE registers, contl ushort4 reads, AgErot in LDS) with ONE change:
// no LDS staging of q/tables -- bias dots read Qb/frow/fcol/gemb straight
// from global (L2-hot). R11's register-lifting (Ep[28] + unrolled 4v passes)
// caused scratch spills (WRITE_SIZE 19.6->97 MB) and is NOT retained.
// Block = (b,h,i,jhalf): 28 query rows (4 g x 7 j) vs 784 keys.
// ============================================================
__global__ __launch_bounds__(256, 2)
void k_attn(const __hip_bfloat16* __restrict__ Qb, const __hip_bfloat16* __restrict__ Kb,
            const float* __restrict__ frow_g, const float* __restrict__ fcol_g,
            const float* __restrict__ gemb_g, __hip_bfloat16* __restrict__ Pb) {
  const int tid = threadIdx.x;
  const int bid = blockIdx.x;
  const int jhalf = bid & 1;
  const int t2 = bid >> 1;
  const int qi = t2 % 14;
  const int hh = (t2 / 14) % 8;
  const int bb = t2 / 112;
  const int bh = bb*8 + hh;

  __shared__ float Arr2[kQR][27];             // row bias dot * kK2
  __shared__ float Acl2[kQR][27];             // col bias dot * kK2
  __shared__ float AgE[kQR][4];               // exp2(group bias * kK2)
  __shared__ float AgErot[kQR][4];            // per-v rotated AgE
  __shared__ float redw[kQR][4];
  __shared__ float DinvS[kQR];
  __shared__ alignas(16) __hip_bfloat16 contl[kQR][kCL];  // E: [q][ij*4 + m]

  const short* Qs = (const short*)Qb;
  const short* Ks = (const short*)Kb;

  // ---- MFMA content GEMM -> contl (E = exp2(content*kK2 - Cc), bf16)
  {
    const int lane = tid & 63;
    const int wave = tid >> 6;
    const int col  = lane & 15;
    const int quad = lane >> 4;

    bf16x8 afrag[2][3];
#pragma unroll
    for (int mt = 0; mt < 2; ++mt) {
      int m = mt*16 + col;
      int q = (m < kQR) ? m : 0;                 // pad rows: duplicate q0 (discarded)
      const short* qrow = Qs +
          ((size_t)((bh*4 + q/7)*kSS + qi*14 + jhalf*7 + q%7))*96;
#pragma unroll
      for (int ks = 0; ks < 3; ++ks)
        afrag[mt][ks] = *(const bf16x8*)(qrow + ks*32 + quad*8);
    }

    for (int nt = wave; nt < 49; nt += 4) {
      int kl = nt*16 + col;                      // key index g_key*196 + ij
      const short* krow = Ks + ((size_t)(bh*kKey + kl))*96;
      bf16x8 b0 = *(const bf16x8*)(krow + 0*32 + quad*8);
      bf16x8 b1 = *(const bf16x8*)(krow + 1*32 + quad*8);
      bf16x8 b2 = *(const bf16x8*)(krow + 2*32 + quad*8);
      f32x4 c0 = {0.f,0.f,0.f,0.f};
      f32x4 c1 = {0.f,0.f,0.f,0.f};
      c0 = __builtin_amdgcn_mfma_f32_16x16x32_bf16(afrag[0][0], b0, c0, 0, 0, 0);
      c0 = __builtin_amdgcn_mfma_f32_16x16x32_bf16(afrag[0][1], b1, c0, 0, 0, 0);
      c0 = __builtin_amdgcn_mfma_f32_16x16x32_bf16(afrag[0][2], b2, c0, 0, 0, 0);
      c1 = __builtin_amdgcn_mfma_f32_16x16x32_bf16(afrag[1][0], b0, c1, 0, 0, 0);
      c1 = __builtin_amdgcn_mfma_f32_16x16x32_bf16(afrag[1][1], b1, c1, 0, 0, 0);
      c1 = __builtin_amdgcn_mfma_f32_16x16x32_bf16(afrag[1][2], b2, c1, 0, 0, 0);
      int ijn = kl % 196, mk = kl / 196;         // interleaved store position
      // C/D layout: col = lane&15 (=kl), row = quad*4 + r (=q)  [m89]
#pragma unroll
      for (int r = 0; r < 4; ++r) {
        int q0 = quad*4 + r;                     // 0..15, all valid
        contl[q0][ijn*4 + mk] = __float2bfloat16(exp2f(c0[r]*kK2 - kCc));
        int q1 = 16 + quad*4 + r;                // 16..31, valid < 28
        if (q1 < kQR)
          contl[q1][ijn*4 + mk] = __float2bfloat16(exp2f(c1[r]*kK2 - kCc));
      }
    }
  }

  // ---- per-query bias tables, read straight from global (L2-hot)
  for (int t = tid; t < kQR*58; t += 256) {
    int q = t / 58, s = t - q*58;
    int gq = q / 7, jq = q - gq*7;
    const __hip_bfloat16* qrow =
        Qb + ((size_t)((bh*4 + gq)*kSS + qi*14 + jhalf*7 + jq))*96;
    float acc = 0.f;
    if (s < 27) {
#pragma unroll
      for (int c = 0; c < 32; ++c)
        acc += __bfloat162float(qrow[c]) * frow_g[s*32 + c];
      Arr2[q][s] = acc * kK2;
    } else if (s < 54) {
      int n = s - 27;
#pragma unroll
      for (int c = 0; c < 32; ++c)
        acc += __bfloat162float(qrow[32 + c]) * fcol_g[n*32 + c];
      Acl2[q][n] = acc * kK2;
    } else {
      int p = s - 54;
#pragma unroll
      for (int c = 0; c < 32; ++c)
        acc += __bfloat162float(qrow[64 + c]) * gemb_g[p*32 + c];
      AgE[q][p] = exp2f(acc * kK2);
    }
  }
  __syncthreads();

  const int kk = (tid < 196) ? (tid / 14) : 0;
  const int ll = (tid < 196) ? (tid % 14) : 0;
  const int da = kk - qi;

  for (int v = 0; v < 4; ++v) {
    int s1a, s1b, s2a, s2b;
    if (v == 0)      { s1a = 1;  s1b = 0;  s2a = 0;  s2b = 1;  }
    else if (v == 1) { s1a = 0;  s1b = -1; s2a = 1;  s2b = 0;  }
    else if (v == 2) { s1a = -1; s1b = 0;  s2a = 0;  s2b = -1; }
    else             { s1a = 0;  s1b = 1;  s2a = -1; s2b = 0;  }

    if (tid < 112) {
      int q = tid >> 2, m = tid & 3, gq = q / 7;
      AgErot[q][m] = AgE[q][(m - gq + v + 8) & 3];
    }
    __syncthreads();

    // ---- pass B: denominators. Vectorized contl read, ILP shuffle-reduce.
    float arvE[kQR];
    float prt[kQR];
    if (tid < 196) {
#pragma unroll
      for (int gq = 0; gq < 4; ++gq) {
#pragma unroll
        for (int jq = 0; jq < 7; ++jq) {
          const int q = gq*7 + jq;
          const int db = ll - (jhalf*7 + jq);
          const int ai = s1a*da + s1b*db, ci = s2a*da + s2b*db;
          arvE[q] = exp2f(Arr2[q][13 + ai] + Acl2[q][13 + ci]);
          ushort4 u = *(const ushort4*)(&contl[q][tid*4]);
          float e0 = __uint_as_float((unsigned)u.x << 16);
          float e1 = __uint_as_float((unsigned)u.y << 16);
          float e2 = __uint_as_float((unsigned)u.z << 16);
          float e3 = __uint_as_float((unsigned)u.w << 16);
          prt[q] = (e0*AgErot[q][0] + e1*AgErot[q][1] +
                    e2*AgErot[q][2] + e3*AgErot[q][3]) * arvE[q];
        }
      }
    } else {
#pragma unroll
      for (int q = 0; q < kQR; ++q) { prt[q] = 0.f; arvE[q] = 0.f; }
    }
    // level-outer butterfly: 28 independent shuffles per level (ILP)
#pragma unroll
    for (int off = 1; off < 64; off <<= 1) {
#pragma unroll
      for (int q = 0; q < kQR; ++q)
        prt[q] += __shfl_xor(prt[q], off, 64);
    }
    if ((tid & 63) == 0) {
#pragma unroll
      for (int q = 0; q < kQR; ++q) redw[q][tid >> 6] = prt[q];
    }
    __syncthreads();
    if (tid < kQR)
      DinvS[tid] = 1.0f / (redw[tid][0] + redw[tid][1] + redw[tid][2] + redw[tid][3]);
    __syncthreads();

    // ---- pass C: normalized probs (no transcendentals), summed over g.
    // Stored bf16, row stride 800 (MFMA A-operand layout for k_pv).
    if (tid < 196) {
      __hip_bfloat16* pbase =
          Pb + ((size_t)((bh*4 + v)*kSS + qi*14 + jhalf*7))*kKeyP + tid;
#pragma unroll
      for (int jq = 0; jq < 7; ++jq) {
        float am[4] = {0.f, 0.f, 0.f, 0.f};
#pragma unroll
        for (int gq = 0; gq < 4; ++gq) {
          const int q = gq*7 + jq;
          const float fq = arvE[q] * DinvS[q];
          ushort4 u = *(const ushort4*)(&contl[q][tid*4]);
          float e0 = __uint_as_float((unsigned)u.x << 16);
          float e1 = __uint_as_float((unsigned)u.y << 16);
          float e2 = __uint_as_float((unsigned)u.z << 16);
          float e3 = __uint_as_float((unsigned)u.w << 16);
          am[0] += e0 * (AgErot[q][0] * fq);
          am[1] += e1 * (AgErot[q][1] * fq);
          am[2] += e2 * (AgErot[q][2] * fq);
          am[3] += e3 * (AgErot[q][3] * fq);
        }
        __hip_bfloat16* pp = pbase + (size_t)jq*kKeyP;
#pragma unroll
        for (int m = 0; m < 4; ++m) pp[m*196] = __float2bfloat16(am[m]);
      }
    }
    // zero the key-pad [784,800) of this block's 7 rows for this v
    if (tid < 112) {
      int jq = tid >> 4, kp = tid & 15;
      Pb[((size_t)((bh*4 + v)*kSS + qi*14 + jhalf*7 + jq))*kKeyP + kKey + kp] =
          __float2bfloat16(0.f);
    }
    __syncthreads();   // protects AgErot for next v
  }
}

// ============================================================
// Kernel 3: PV + per-head partial output projection (R10-proven, unchanged).
// ============================================================
__global__ __launch_bounds__(128)
void k_pv(const __hip_bfloat16* __restrict__ Pb,
          const __hip_bfloat16* __restrict__ Vb,
          const __hip_bfloat16* __restrict__ Woh,
          const float* __restrict__ bo, float* __restrict__ out) {
  const int tid  = threadIdx.x;
  const int lane = tid & 63;
  const int wave = tid >> 6;
  const int bh = blockIdx.x / 49;
  const int mt = blockIdx.x % 49;
  const int mrow = lane & 15;
  const int quad = lane >> 4;
  const int b_ = bh >> 3, h_ = bh & 7;

  __shared__ alignas(16) __hip_bfloat16 vos[16][104];  // [m-row][c], pad 96->104

  // ---- phase A: PV (this head), 6 N-tiles split 3 per wave
  {
    const short* Ap = (const short*)Pb +
        ((size_t)(bh*kKey + mt*16 + mrow))*kKeyP + quad*8;
    const short* Bp = (const short*)Vb + ((size_t)bh*96)*kKeyP + quad*8;

    f32x4 acc0 = {0.f,0.f,0.f,0.f};
    f32x4 acc1 = {0.f,0.f,0.f,0.f};
    f32x4 acc2 = {0.f,0.f,0.f,0.f};
    const int n0 = (wave*3 + 0)*16 + mrow;
    const int n1 = (wave*3 + 1)*16 + mrow;
    const int n2 = (wave*3 + 2)*16 + mrow;

    for (int ks = 0; ks < kKeyP/32; ++ks) {
      bf16x8 a  = *(const bf16x8*)(Ap + ks*32);
      bf16x8 b0 = *(const bf16x8*)(Bp + (size_t)n0*kKeyP + ks*32);
      bf16x8 b1 = *(const bf16x8*)(Bp + (size_t)n1*kKeyP + ks*32);
      bf16x8 b2 = *(const bf16x8*)(Bp + (size_t)n2*kKeyP + ks*32);
      acc0 = __builtin_amdgcn_mfma_f32_16x16x32_bf16(a, b0, acc0, 0, 0, 0);
      acc1 = __builtin_amdgcn_mfma_f32_16x16x32_bf16(a, b1, acc1, 0, 0, 0);
      acc2 = __builtin_amdgcn_mfma_f32_16x16x32_bf16(a, b2, acc2, 0, 0, 0);
    }
    // C/D: col = lane&15 (= c within n-tile), row = quad*4 + r (= m-row)
#pragma unroll
    for (int r = 0; r < 4; ++r) {
      vos[quad*4 + r][n0] = __float2bfloat16(acc0[r]);
      vos[quad*4 + r][n1] = __float2bfloat16(acc1[r]);
      vos[quad*4 + r][n2] = __float2bfloat16(acc2[r]);
    }
  }
  __syncthreads();

  // ---- phase B: partial outproj for this head, 6 d-tiles split 3 per wave
  const short* wb = (const short*)Woh + (size_t)h_*9216;
#pragma unroll
  for (int w = 0; w < 3; ++w) {
    const int dt = wave*3 + w;
    f32x4 acc = {0.f,0.f,0.f,0.f};
#pragma unroll
    for (int ks = 0; ks < 3; ++ks) {
      bf16x8 a  = *(const bf16x8*)(&vos[mrow][ks*32 + quad*8]);
      bf16x8 bf = *(const bf16x8*)(wb + (size_t)(dt*16 + mrow)*96 + ks*32 + quad*8);
      acc = __builtin_amdgcn_mfma_f32_16x16x32_bf16(a, bf, acc, 0, 0, 0);
    }
    const int d = dt*16 + mrow;                 // D col = lane&15 = d-in-tile
    const float bias = (h_ == 0) ? bo[d] : 0.f;
#pragma unroll
    for (int r = 0; r < 4; ++r) {
      int m = mt*16 + quad*4 + r;
      int v = m / kSS, ij = m - v*kSS;
      atomicAdd(&out[((size_t)(b_*96 + d)*4 + v)*kSS + ij], acc[r] + bias);
    }
  }
}

// ============================================================
extern "C" void kernel_launch(void* const* d_in, const int* in_sizes, int n_in,
                              void* d_out, int out_size, void* d_ws, size_t ws_size,
                              hipStream_t stream) {
  const float* x    = (const float*)d_in[0];
  const float* Wq   = (const float*)d_in[1];
  const float* bq   = (const float*)d_in[2];
  const float* Wk   = (const float*)d_in[3];
  const float* bk   = (const float*)d_in[4];
  const float* Wv   = (const float*)d_in[5];
  const float* bv   = (const float*)d_in[6];
  const float* Wo   = (const float*)d_in[7];
  const float* bo   = (const float*)d_in[8];
  const float* rw1  = (const float*)d_in[9];
  const float* rb1  = (const float*)d_in[10];
  const float* rgam = (const float*)d_in[11];
  const float* rbet = (const float*)d_in[12];
  const float* rw2  = (const float*)d_in[13];
  const float* rb2  = (const float*)d_in[14];
  const float* cw1  = (const float*)d_in[15];
  const float* cb1  = (const float*)d_in[16];
  const float* cgam = (const float*)d_in[17];
  const float* cbet = (const float*)d_in[18];
  const float* cw2  = (const float*)d_in[19];
  const float* cb2  = (const float*)d_in[20];
  const float* gemb = (const float*)d_in[21];
  // d_in[22..24] = row_rel, col_rel, g_idx: reconstructed analytically.

  float* ws = (float*)d_ws;
  __hip_bfloat16* Qb = (__hip_bfloat16*)(ws + OFF_Qb);
  __hip_bfloat16* Kb = (__hip_bfloat16*)(ws + OFF_Kb);
  __hip_bfloat16* Vb = (__hip_bfloat16*)(ws + OFF_V);
  float* Frow = ws + OFF_FR;
  float* Fcol = ws + OFF_FC;
  __hip_bfloat16* Pb = (__hip_bfloat16*)(ws + OFF_PS);
  __hip_bfloat16* Woh = (__hip_bfloat16*)(ws + OFF_WOH);
  float* out  = (float*)d_out;

  k_qkv<<<dim3(112, 3), 256, 0, stream>>>(x, Wq, bq, Wk, bk, Wv, bv, Qb, Kb, Vb,
                                          rw1, rb1, rgam, rbet, rw2, rb2,
                                          cw1, cb1, cgam, cbet, cw2, cb2,
                                          Frow, Fcol, Wo, Woh, out);
  k_attn<<<448, 256, 0, stream>>>(Qb, Kb, Frow, Fcol, gemb, Pb);
  k_pv<<<784, 128, 0, stream>>>(Pb, Vb, Woh, bo, out);
}

// Round 13
// 224.003 us; speedup vs baseline: 1.3007x; 1.0292x over previous
//
#include <hip/hip_runtime.h>
#include <hip/hip_bf16.h>

// Problem constants
constexpr int kB   = 2;
constexpr int kH   = 8;
constexpr int kG   = 4;
constexpr int kS   = 14;
constexpr int kSS  = 196;   // S*S
constexpr int kKey = 784;   // G*S*S keys per (b,h)
constexpr int kKeyP = 800;  // keys padded to multiple of 32 for MFMA K-loop
constexpr int kMid = 96;
constexpr int kQR  = 28;    // 4 g * 7 j query rows per attention block
constexpr int kCL  = 788;   // contl row stride in u16 = 197*4 ([ij][m] interleaved)
constexpr float kScl = 0.10206207261596577f; // 1/sqrt(96)
constexpr float kK2  = 0.14724663682f;       // kScl / ln(2)  (exp2 domain)
constexpr float kCc  = 11.5415603272f;       // 8 nats / ln(2): constant softmax shift (exact)

typedef __attribute__((ext_vector_type(8))) short bf16x8;
typedef __attribute__((ext_vector_type(4))) float f32x4;

// ---------------- workspace layout (float elements) ----------------
constexpr size_t SZ_QKb = (size_t)kB*kH*kG*kSS*kMid/2; // 602,112 (bf16 in float units)
constexpr size_t OFF_Qb = 0;                            // Qb bf16 [bh][g*196+ij][96]
constexpr size_t OFF_Kb = OFF_Qb + SZ_QKb;              // Kb bf16 [bh][g*196+ij][96]
constexpr size_t OFF_V  = OFF_Kb + SZ_QKb;              // Vb bf16 CHANNEL-MAJOR [bh][c][800]
constexpr size_t SZ_V   = (size_t)kB*kH*kMid*kKeyP/2;   // 614,400
constexpr size_t OFF_FR = OFF_V + SZ_V;                 // 27*32 row table fp32
constexpr size_t OFF_FC = OFF_FR + 27*32;               // 27*32 col table fp32
constexpr size_t OFF_PS = OFF_FC + 27*32;               // Psum bf16 [bh][v*196+ij][800]
constexpr size_t SZ_PS  = (size_t)kB*kH*kG*kSS*kKeyP/2; // 5,017,600
constexpr size_t OFF_WOH = OFF_PS + SZ_PS;              // Woh bf16 [h][d][c] (73,728)

// ============================================================
// Kernel 1: QKV projection + fused setup (R10-proven).
// Q,K bf16 key-major [bh][g*196+ij][96] (MFMA A/B^T layout for k_attn).
// V bf16 CHANNEL-MAJOR [bh][c][800] (MFMA B layout for k_pv).
// d = c*8 + h per the reference reshape(MID, HEADS).
// Fused tails: all blocks zero d_out (k_pv accumulates with atomics);
// ten==1 blocks convert Wo -> per-head bf16 Woh[h][d][c] (= Wo[d][c*8+h]);
// ten==2 bid<16 zero V key-pad; ten==0 bid==0 computes the 27x32 embed tables.
// ============================================================
__global__ __launch_bounds__(256)
void k_qkv(const float* __restrict__ x,
           const float* __restrict__ Wq, const float* __restrict__ bq,
           const float* __restrict__ Wk, const float* __restrict__ bk,
           const float* __restrict__ Wv, const float* __restrict__ bv,
           __hip_bfloat16* __restrict__ Qb, __hip_bfloat16* __restrict__ Kb,
           __hip_bfloat16* __restrict__ Vb,
           const float* __restrict__ rw1, const float* __restrict__ rb1,
           const float* __restrict__ rgam, const float* __restrict__ rbet,
           const float* __restrict__ rw2, const float* __restrict__ rb2,
           const float* __restrict__ cw1, const float* __restrict__ cb1,
           const float* __restrict__ cgam, const float* __restrict__ cbet,
           const float* __restrict__ cw2, const float* __restrict__ cb2,
           float* __restrict__ frow, float* __restrict__ fcol,
           const float* __restrict__ Wo, __hip_bfloat16* __restrict__ Woh,
           float* __restrict__ out0) {
  const int bid = blockIdx.x;
  const int ten = blockIdx.y;
  const int i = bid % 14;
  const int g = (bid / 14) % 4;
  const int b = bid / 56;
  const float* W    = (ten == 0) ? Wq : (ten == 1) ? Wk : Wv;
  const float* bias = (ten == 0) ? bq : (ten == 1) ? bk : bv;

  // ---- zero d_out (atomically accumulated by k_pv; harness poisons it)
  {
    int zidx = (ten*112 + bid)*256 + threadIdx.x;   // 0 .. 86015
    if (zidx < 37632) ((float4*)out0)[zidx] = make_float4(0.f, 0.f, 0.f, 0.f);
  }

  __shared__ alignas(16) float xs[14][100];   // transposed, padded
  for (int idx = threadIdx.x; idx < 96*14; idx += 256) {
    int cin = idx / 14, j = idx % 14;
    xs[j][cin] = x[((size_t)(b*96 + cin)*4 + g)*196 + i*14 + j];
  }
  __syncthreads();

  for (int d = threadIdx.x; d < 768; d += 256) {
    int c = d >> 3, h = d & 7;
    float bvv = bias[d];
    float acc[14];
#pragma unroll
    for (int j = 0; j < 14; ++j) acc[j] = bvv;
    const float* wrow = W + (size_t)d * 96;
    for (int cc = 0; cc < 96; cc += 4) {
      float4 w = *(const float4*)(wrow + cc);
#pragma unroll
      for (int j = 0; j < 14; ++j) {
        float4 xv = *(const float4*)(&xs[j][cc]);
        acc[j] += w.x*xv.x + w.y*xv.y + w.z*xv.z + w.w*xv.w;
      }
    }
    if (ten == 2) {
      __hip_bfloat16* op = Vb + ((size_t)((b*8 + h)*96 + c))*kKeyP + g*196 + i*14;
#pragma unroll
      for (int j = 0; j < 14; ++j) op[j] = __float2bfloat16(acc[j]);
    } else {
      __hip_bfloat16* dst = (ten == 0) ? Qb : Kb;
      __hip_bfloat16* op = dst + ((size_t)((b*8 + h)*4 + g)*196 + i*14)*96 + c;
#pragma unroll
      for (int j = 0; j < 14; ++j) op[(size_t)j*96] = __float2bfloat16(acc[j]);
    }
  }

  // ---- fused setup tails ----
  if (ten == 1) {
    // Woh[h][d][c] = bf16(Wo[d][c*8+h]) -- per-head B-operand for k_pv phase B
    for (int idx = bid*256 + threadIdx.x; idx < 73728; idx += 112*256) {
      int h = idx / 9216, rem = idx - h*9216;
      int d = rem / 96, c = rem - d*96;
      Woh[idx] = __float2bfloat16(Wo[(size_t)d*768 + c*8 + h]);
    }
  }
  if (ten == 2 && bid < 16) {
    // zero V key-pad for bh = bid
    for (int idx = threadIdx.x; idx < 96*16; idx += 256) {
      int c = idx >> 4, kp = idx & 15;
      Vb[((size_t)(bid*96 + c))*kKeyP + kKey + kp] = __float2bfloat16(0.f);
    }
  }
  if (ten == 0 && bid == 0 && threadIdx.x < 54) {
    int t = threadIdx.x;
    int which = t / 27;
    int n = t % 27;
    float tv = (float)(n - 13) / 13.0f;
    const float* w1  = which ? cw1  : rw1;
    const float* b1  = which ? cb1  : rb1;
    const float* gam = which ? cgam : rgam;
    const float* bet = which ? cbet : rbet;
    const float* w2  = which ? cw2  : rw2;
    const float* b2  = which ? cb2  : rb2;
    float h[16];
    float mu = 0.f;
#pragma unroll
    for (int d = 0; d < 16; ++d) { h[d] = tv * w1[d] + b1[d]; mu += h[d]; }
    mu *= (1.0f/16.0f);
    float var = 0.f;
#pragma unroll
    for (int d = 0; d < 16; ++d) { float z = h[d] - mu; var += z*z; }
    var *= (1.0f/16.0f);
    float rstd = rsqrtf(var + 1e-5f);
#pragma unroll
    for (int d = 0; d < 16; ++d) {
      float z = (h[d] - mu) * rstd * gam[d] + bet[d];
      h[d] = z / (1.0f + expf(-z));   // silu
    }
    float* outp = (which ? fcol : frow) + n*32;
    for (int c = 0; c < 32; ++c) {
      float o = b2[c];
#pragma unroll
      for (int d = 0; d < 16; ++d) o += h[d] * w2[d*32 + c];
      outp[c] = o;
    }
  }
}

// ============================================================
// Kernel 2: fused content + bias + softmax (R10-proven, measured optimum:
// 59.8 us). LDS-staged q/tables for the bias dots (R12's global-read variant
// regressed to 66.4 us: 52k scattered 2-byte loads/block); per-v loop with
// arvE in registers (R11's all-v register lifting spilled to scratch).
// MFMA QK^T -> contl [q][ij*4+m]; level-outer ILP shuffle reduction.
// Block = (b,h,i,jhalf): 28 query rows (4 g x 7 j) vs 784 keys.
// ============================================================
__global__ __launch_bounds__(256, 2)
void k_attn(const __hip_bfloat16* __restrict__ Qb, const __hip_bfloat16* __restrict__ Kb,
            const float* __restrict__ frow_g, const float* __restrict__ fcol_g,
            const float* __restrict__ gemb_g, __hip_bfloat16* __restrict__ Pb) {
  const int tid = threadIdx.x;
  const int bid = blockIdx.x;
  const int jhalf = bid & 1;
  const int t2 = bid >> 1;
  const int qi = t2 % 14;
  const int hh = (t2 / 14) % 8;
  const int bb = t2 / 112;
  const int bh = bb*8 + hh;

  __shared__ alignas(16) float qs[kQR][96];   // fp32 copies for bias dots
  __shared__ alignas(16) float frowS[27*32];
  __shared__ alignas(16) float fcolS[27*32];
  __shared__ alignas(16) float gembS[128];
  __shared__ float Arr2[kQR][27];             // row bias dot, pre-scaled by kK2
  __shared__ float Acl2[kQR][27];             // col bias dot, pre-scaled by kK2
  __shared__ float AgE[kQR][4];               // exp2(group bias * kK2)
  __shared__ float AgErot[kQR][4];            // per-v rotated AgE
  __shared__ float redw[kQR][4];
  __shared__ float DinvS[kQR];
  __shared__ alignas(16) __hip_bfloat16 contl[kQR][kCL];  // E: [q][ij*4 + m]

  const short* Qs = (const short*)Qb;
  const short* Ks = (const short*)Kb;

  // ---- stage fp32 query copies + tables (tables pre-scaled into exp2 domain)
  for (int idx = tid; idx < kQR*96; idx += 256) {
    int q = idx / 96, c = idx - q*96;
    int g = q / 7, jq = q - g*7;
    qs[q][c] = __bfloat162float(
        Qb[((size_t)((bh*4 + g)*kSS + qi*14 + jhalf*7 + jq))*96 + c]);
  }
  for (int idx = tid; idx < 864; idx += 256) frowS[idx] = frow_g[idx] * kK2;
  for (int idx = tid; idx < 864; idx += 256) fcolS[idx] = fcol_g[idx] * kK2;
  if (tid < 128) gembS[tid] = gemb_g[tid] * kK2;
  __syncthreads();

  // ---- MFMA content GEMM -> contl (E = exp2(content*kK2 - Cc), bf16)
  {
    const int lane = tid & 63;
    const int wave = tid >> 6;
    const int col  = lane & 15;
    const int quad = lane >> 4;

    bf16x8 afrag[2][3];
#pragma unroll
    for (int mt = 0; mt < 2; ++mt) {
      int m = mt*16 + col;
      int q = (m < kQR) ? m : 0;                 // pad rows: duplicate q0 (discarded)
      const short* qrow = Qs +
          ((size_t)((bh*4 + q/7)*kSS + qi*14 + jhalf*7 + q%7))*96;
#pragma unroll
      for (int ks = 0; ks < 3; ++ks)
        afrag[mt][ks] = *(const bf16x8*)(qrow + ks*32 + quad*8);
    }

    for (int nt = wave; nt < 49; nt += 4) {
      int kl = nt*16 + col;                      // key index g_key*196 + ij
      const short* krow = Ks + ((size_t)(bh*kKey + kl))*96;
      bf16x8 b0 = *(const bf16x8*)(krow + 0*32 + quad*8);
      bf16x8 b1 = *(const bf16x8*)(krow + 1*32 + quad*8);
      bf16x8 b2 = *(const bf16x8*)(krow + 2*32 + quad*8);
      f32x4 c0 = {0.f,0.f,0.f,0.f};
      f32x4 c1 = {0.f,0.f,0.f,0.f};
      c0 = __builtin_amdgcn_mfma_f32_16x16x32_bf16(afrag[0][0], b0, c0, 0, 0, 0);
      c0 = __builtin_amdgcn_mfma_f32_16x16x32_bf16(afrag[0][1], b1, c0, 0, 0, 0);
      c0 = __builtin_amdgcn_mfma_f32_16x16x32_bf16(afrag[0][2], b2, c0, 0, 0, 0);
      c1 = __builtin_amdgcn_mfma_f32_16x16x32_bf16(afrag[1][0], b0, c1, 0, 0, 0);
      c1 = __builtin_amdgcn_mfma_f32_16x16x32_bf16(afrag[1][1], b1, c1, 0, 0, 0);
      c1 = __builtin_amdgcn_mfma_f32_16x16x32_bf16(afrag[1][2], b2, c1, 0, 0, 0);
      int ijn = kl % 196, mk = kl / 196;         // interleaved store position
      // C/D layout: col = lane&15 (=kl), row = quad*4 + r (=q)  [m89]
#pragma unroll
      for (int r = 0; r < 4; ++r) {
        int q0 = quad*4 + r;                     // 0..15, all valid
        contl[q0][ijn*4 + mk] = __float2bfloat16(exp2f(c0[r]*kK2 - kCc));
        int q1 = 16 + quad*4 + r;                // 16..31, valid < 28
        if (q1 < kQR)
          contl[q1][ijn*4 + mk] = __float2bfloat16(exp2f(c1[r]*kK2 - kCc));
      }
    }
  }

  // ---- per-query bias tables (exp2 domain)
  for (int t = tid; t < kQR*58; t += 256) {
    int q = t / 58, s = t - q*58;
    float acc = 0.f;
    if (s < 27) {
#pragma unroll
      for (int c = 0; c < 32; ++c) acc += qs[q][c] * frowS[s*32 + c];
      Arr2[q][s] = acc;
    } else if (s < 54) {
      int n = s - 27;
#pragma unroll
      for (int c = 0; c < 32; ++c) acc += qs[q][32+c] * fcolS[n*32 + c];
      Acl2[q][n] = acc;
    } else {
      int p = s - 54;
#pragma unroll
      for (int c = 0; c < 32; ++c) acc += qs[q][64+c] * gembS[p*32 + c];
      AgE[q][p] = exp2f(acc);
    }
  }
  __syncthreads();

  const int kk = (tid < 196) ? (tid / 14) : 0;
  const int ll = (tid < 196) ? (tid % 14) : 0;
  const int da = kk - qi;

  for (int v = 0; v < 4; ++v) {
    int s1a, s1b, s2a, s2b;
    if (v == 0)      { s1a = 1;  s1b = 0;  s2a = 0;  s2b = 1;  }
    else if (v == 1) { s1a = 0;  s1b = -1; s2a = 1;  s2b = 0;  }
    else if (v == 2) { s1a = -1; s1b = 0;  s2a = 0;  s2b = -1; }
    else             { s1a = 0;  s1b = 1;  s2a = -1; s2b = 0;  }

    if (tid < 112) {
      int q = tid >> 2, m = tid & 3, gq = q / 7;
      AgErot[q][m] = AgE[q][(m - gq + v + 8) & 3];
    }
    __syncthreads();

    // ---- pass B: denominators. Vectorized contl read, ILP shuffle-reduce.
    float arvE[kQR];
    float prt[kQR];
    if (tid < 196) {
#pragma unroll
      for (int gq = 0; gq < 4; ++gq) {
#pragma unroll
        for (int jq = 0; jq < 7; ++jq) {
          const int q = gq*7 + jq;
          const int db = ll - (jhalf*7 + jq);
          const int ai = s1a*da + s1b*db, ci = s2a*da + s2b*db;
          arvE[q] = exp2f(Arr2[q][13 + ai] + Acl2[q][13 + ci]);
          ushort4 u = *(const ushort4*)(&contl[q][tid*4]);
          float e0 = __uint_as_float((unsigned)u.x << 16);
          float e1 = __uint_as_float((unsigned)u.y << 16);
          float e2 = __uint_as_float((unsigned)u.z << 16);
          float e3 = __uint_as_float((unsigned)u.w << 16);
          prt[q] = (e0*AgErot[q][0] + e1*AgErot[q][1] +
                    e2*AgErot[q][2] + e3*AgErot[q][3]) * arvE[q];
        }
      }
    } else {
#pragma unroll
      for (int q = 0; q < kQR; ++q) { prt[q] = 0.f; arvE[q] = 0.f; }
    }
    // level-outer butterfly: 28 independent shuffles per level (ILP)
#pragma unroll
    for (int off = 1; off < 64; off <<= 1) {
#pragma unroll
      for (int q = 0; q < kQR; ++q)
        prt[q] += __shfl_xor(prt[q], off, 64);
    }
    if ((tid & 63) == 0) {
#pragma unroll
      for (int q = 0; q < kQR; ++q) redw[q][tid >> 6] = prt[q];
    }
    __syncthreads();
    if (tid < kQR)
      DinvS[tid] = 1.0f / (redw[tid][0] + redw[tid][1] + redw[tid][2] + redw[tid][3]);
    __syncthreads();

    // ---- pass C: normalized probs (no transcendentals), summed over g.
    // Stored bf16, row stride 800 (MFMA A-operand layout for k_pv).
    if (tid < 196) {
      __hip_bfloat16* pbase =
          Pb + ((size_t)((bh*4 + v)*kSS + qi*14 + jhalf*7))*kKeyP + tid;
#pragma unroll
      for (int jq = 0; jq < 7; ++jq) {
        float am[4] = {0.f, 0.f, 0.f, 0.f};
#pragma unroll
        for (int gq = 0; gq < 4; ++gq) {
          const int q = gq*7 + jq;
          const float fq = arvE[q] * DinvS[q];
          ushort4 u = *(const ushort4*)(&contl[q][tid*4]);
          float e0 = __uint_as_float((unsigned)u.x << 16);
          float e1 = __uint_as_float((unsigned)u.y << 16);
          float e2 = __uint_as_float((unsigned)u.z << 16);
          float e3 = __uint_as_float((unsigned)u.w << 16);
          am[0] += e0 * (AgErot[q][0] * fq);
          am[1] += e1 * (AgErot[q][1] * fq);
          am[2] += e2 * (AgErot[q][2] * fq);
          am[3] += e3 * (AgErot[q][3] * fq);
        }
        __hip_bfloat16* pp = pbase + (size_t)jq*kKeyP;
#pragma unroll
        for (int m = 0; m < 4; ++m) pp[m*196] = __float2bfloat16(am[m]);
      }
    }
    // zero the key-pad [784,800) of this block's 7 rows for this v
    if (tid < 112) {
      int jq = tid >> 4, kp = tid & 15;
      Pb[((size_t)((bh*4 + v)*kSS + qi*14 + jhalf*7 + jq))*kKeyP + kKey + kp] =
          __float2bfloat16(0.f);
    }
    __syncthreads();   // protects AgErot for next v
  }
}

// ============================================================
// Kernel 3: PV + per-head partial output projection (R10-proven, unchanged).
// Block = (bh, mt): 784 blocks x 128 thr -> ~3 blocks/CU.
// Phase A: vo_h[16x96] = P[16x800] . V[800x96] -> bf16 LDS.
// Phase B: partial out[16x96] = vo_h . Woh[h]^T (+ bo if h==0), atomicAdd.
// ============================================================
__global__ __launch_bounds__(128)
void k_pv(const __hip_bfloat16* __restrict__ Pb,
          const __hip_bfloat16* __restrict__ Vb,
          const __hip_bfloat16* __restrict__ Woh,
          const float* __restrict__ bo, float* __restrict__ out) {
  const int tid  = threadIdx.x;
  const int lane = tid & 63;
  const int wave = tid >> 6;
  const int bh = blockIdx.x / 49;
  const int mt = blockIdx.x % 49;
  const int mrow = lane & 15;
  const int quad = lane >> 4;
  const int b_ = bh >> 3, h_ = bh & 7;

  __shared__ alignas(16) __hip_bfloat16 vos[16][104];  // [m-row][c], pad 96->104

  // ---- phase A: PV (this head), 6 N-tiles split 3 per wave
  {
    const short* Ap = (const short*)Pb +
        ((size_t)(bh*kKey + mt*16 + mrow))*kKeyP + quad*8;
    const short* Bp = (const short*)Vb + ((size_t)bh*96)*kKeyP + quad*8;

    f32x4 acc0 = {0.f,0.f,0.f,0.f};
    f32x4 acc1 = {0.f,0.f,0.f,0.f};
    f32x4 acc2 = {0.f,0.f,0.f,0.f};
    const int n0 = (wave*3 + 0)*16 + mrow;
    const int n1 = (wave*3 + 1)*16 + mrow;
    const int n2 = (wave*3 + 2)*16 + mrow;

    for (int ks = 0; ks < kKeyP/32; ++ks) {
      bf16x8 a  = *(const bf16x8*)(Ap + ks*32);
      bf16x8 b0 = *(const bf16x8*)(Bp + (size_t)n0*kKeyP + ks*32);
      bf16x8 b1 = *(const bf16x8*)(Bp + (size_t)n1*kKeyP + ks*32);
      bf16x8 b2 = *(const bf16x8*)(Bp + (size_t)n2*kKeyP + ks*32);
      acc0 = __builtin_amdgcn_mfma_f32_16x16x32_bf16(a, b0, acc0, 0, 0, 0);
      acc1 = __builtin_amdgcn_mfma_f32_16x16x32_bf16(a, b1, acc1, 0, 0, 0);
      acc2 = __builtin_amdgcn_mfma_f32_16x16x32_bf16(a, b2, acc2, 0, 0, 0);
    }
    // C/D: col = lane&15 (= c within n-tile), row = quad*4 + r (= m-row)
#pragma unroll
    for (int r = 0; r < 4; ++r) {
      vos[quad*4 + r][n0] = __float2bfloat16(acc0[r]);
      vos[quad*4 + r][n1] = __float2bfloat16(acc1[r]);
      vos[quad*4 + r][n2] = __float2bfloat16(acc2[r]);
    }
  }
  __syncthreads();

  // ---- phase B: partial outproj for this head, 6 d-tiles split 3 per wave
  const short* wb = (const short*)Woh + (size_t)h_*9216;
#pragma unroll
  for (int w = 0; w < 3; ++w) {
    const int dt = wave*3 + w;
    f32x4 acc = {0.f,0.f,0.f,0.f};
#pragma unroll
    for (int ks = 0; ks < 3; ++ks) {
      bf16x8 a  = *(const bf16x8*)(&vos[mrow][ks*32 + quad*8]);
      bf16x8 bf = *(const bf16x8*)(wb + (size_t)(dt*16 + mrow)*96 + ks*32 + quad*8);
      acc = __builtin_amdgcn_mfma_f32_16x16x32_bf16(a, bf, acc, 0, 0, 0);
    }
    const int d = dt*16 + mrow;                 // D col = lane&15 = d-in-tile
    const float bias = (h_ == 0) ? bo[d] : 0.f;
#pragma unroll
    for (int r = 0; r < 4; ++r) {
      int m = mt*16 + quad*4 + r;
      int v = m / kSS, ij = m - v*kSS;
      atomicAdd(&out[((size_t)(b_*96 + d)*4 + v)*kSS + ij], acc[r] + bias);
    }
  }
}

// ============================================================
extern "C" void kernel_launch(void* const* d_in, const int* in_sizes, int n_in,
                              void* d_out, int out_size, void* d_ws, size_t ws_size,
                              hipStream_t stream) {
  const float* x    = (const float*)d_in[0];
  const float* Wq   = (const float*)d_in[1];
  const float* bq   = (const float*)d_in[2];
  const float* Wk   = (const float*)d_in[3];
  const float* bk   = (const float*)d_in[4];
  const float* Wv   = (const float*)d_in[5];
  const float* bv   = (const float*)d_in[6];
  const float* Wo   = (const float*)d_in[7];
  const float* bo   = (const float*)d_in[8];
  const float* rw1  = (const float*)d_in[9];
  const float* rb1  = (const float*)d_in[10];
  const float* rgam = (const float*)d_in[11];
  const float* rbet = (const float*)d_in[12];
  const float* rw2  = (const float*)d_in[13];
  const float* rb2  = (const float*)d_in[14];
  const float* cw1  = (const float*)d_in[15];
  const float* cb1  = (const float*)d_in[16];
  const float* cgam = (const float*)d_in[17];
  const float* cbet = (const float*)d_in[18];
  const float* cw2  = (const float*)d_in[19];
  const float* cb2  = (const float*)d_in[20];
  const float* gemb = (const float*)d_in[21];
  // d_in[22..24] = row_rel, col_rel, g_idx: reconstructed analytically.

  float* ws = (float*)d_ws;
  __hip_bfloat16* Qb = (__hip_bfloat16*)(ws + OFF_Qb);
  __hip_bfloat16* Kb = (__hip_bfloat16*)(ws + OFF_Kb);
  __hip_bfloat16* Vb = (__hip_bfloat16*)(ws + OFF_V);
  float* Frow = ws + OFF_FR;
  float* Fcol = ws + OFF_FC;
  __hip_bfloat16* Pb = (__hip_bfloat16*)(ws + OFF_PS);
  __hip_bfloat16* Woh = (__hip_bfloat16*)(ws + OFF_WOH);
  float* out  = (float*)d_out;

  k_qkv<<<dim3(112, 3), 256, 0, stream>>>(x, Wq, bq, Wk, bk, Wv, bv, Qb, Kb, Vb,
                                          rw1, rb1, rgam, rbet, rw2, rb2,
                                          cw1, cb1, cgam, cbet, cw2, cb2,
                                          Frow, Fcol, Wo, Woh, out);
  k_attn<<<448, 256, 0, stream>>>(Qb, Kb, Frow, Fcol, gemb, Pb);
  k_pv<<<784, 128, 0, stream>>>(Pb, Vb, Woh, bo, out);
}